// Round 1
// 279.624 us; speedup vs baseline: 1.0633x; 1.0633x over previous
//
#include <hip/hip_runtime.h>
#include <math.h>

#define N 128
#define VOL (N*N*N)            // 2097152
#define PLANE (N*N)            // 16384
#define NKX 65                 // kept x-frequencies 0..64 (Hermitian half)
#define NSHELL 65              // shells 0..64
#define ACC_STRIDE 195         // 3*65 per batch

__device__ __forceinline__ int rev6(int x) { return (int)(__brev((unsigned)x) >> 26); }

__device__ __forceinline__ float2 cmul(float2 a, float2 b) {
    return make_float2(a.x * b.x - a.y * b.y, a.x * b.y + a.y * b.x);
}

// ---- cross-lane exchange layer (VALU-pipe, replaces ds-based __shfl_xor) ----
// h=32/16: gfx950 v_permlane{32,16}_swap_b32. Feeding both operands with
// copies of v yields lo = v[lane & ~h], hi = v[lane | h] in every lane.
__device__ __forceinline__ void plswap32(float2 v, float2& lo, float2& hi) {
    float ax = v.x, bx = v.x, ay = v.y, by = v.y;
    asm("v_permlane32_swap_b32 %0, %1" : "+v"(ax), "+v"(bx));
    asm("v_permlane32_swap_b32 %0, %1" : "+v"(ay), "+v"(by));
    lo = make_float2(ax, ay); hi = make_float2(bx, by);
}
__device__ __forceinline__ void plswap16(float2 v, float2& lo, float2& hi) {
    float ax = v.x, bx = v.x, ay = v.y, by = v.y;
    asm("v_permlane16_swap_b32 %0, %1" : "+v"(ax), "+v"(bx));
    asm("v_permlane16_swap_b32 %0, %1" : "+v"(ay), "+v"(by));
    lo = make_float2(ax, ay); hi = make_float2(bx, by);
}
// h=8: DPP row_ror:8 (== xor8 within 16-lane rows); h=2/1: DPP quad_perm.
template<int CTRL>
__device__ __forceinline__ float2 dpp_xor(float2 v) {
    int rx = __builtin_amdgcn_mov_dpp(__float_as_int(v.x), CTRL, 0xF, 0xF, true);
    int ry = __builtin_amdgcn_mov_dpp(__float_as_int(v.y), CTRL, 0xF, 0xF, true);
    return make_float2(__int_as_float(rx), __int_as_float(ry));
}
// h=4: no DPP/permlane pattern for xor4 -> single ds_swizzle on packed bf16
// (the only remaining LDS op per complex per FFT).
__device__ __forceinline__ float2 swz4(float2 v) {
    unsigned p = __builtin_amdgcn_perm(__float_as_uint(v.y), __float_as_uint(v.x), 0x07060302u);
    unsigned q = (unsigned)__builtin_amdgcn_ds_swizzle((int)p, 0x101F);  // xor 4
    return make_float2(__uint_as_float(q << 16), __uint_as_float(q & 0xFFFF0000u));
}

// bf16x2 pack (RNE) / unpack: complex value in one uint (re low, im high)
__device__ __forceinline__ unsigned int pack_bf2(float2 v) {
    unsigned int r = __float_as_uint(v.x);
    unsigned int i = __float_as_uint(v.y);
    r = (r + 0x7FFFu + ((r >> 16) & 1u)) >> 16;
    i = (i + 0x7FFFu + ((i >> 16) & 1u)) & 0xFFFF0000u;
    return i | r;
}
__device__ __forceinline__ float2 unpack_bf2(unsigned int u) {
    return make_float2(__uint_as_float(u << 16), __uint_as_float(u & 0xFFFF0000u));
}

// fp8 e4m3 packed complex (re byte0, im byte1) for the in-LDS plane
__device__ __forceinline__ unsigned short pack_f8(float2 v) {
    int p = __builtin_amdgcn_cvt_pk_fp8_f32(v.x, v.y, 0, false);
    return (unsigned short)(p & 0xFFFF);
}
__device__ __forceinline__ float2 unpack_f8(unsigned short u) {
    auto r = __builtin_amdgcn_cvt_pk_f32_fp8((int)u, false);
    return make_float2(r[0], r[1]);
}

// 64-entry twiddle table W[m] = e^{-2*pi*i*m/128}, built once per block
__device__ __forceinline__ void build_W(float2* Wsh, int tid) {
    if (tid < 64) {
        float s, c;
        sincosf(-6.283185307179586f * (float)tid / 128.0f, &s, &c);
        Wsh[tid] = make_float2(c, s);
    }
}

// Per-lane effective twiddles: w128 for the register stage; we[i] is the
// stage twiddle for high lanes and (1,0) for low lanes (branchless butterfly).
struct TwE { float2 w128; float2 we[5]; };

__device__ __forceinline__ TwE make_twe(const float2* Wsh, int lane) {
    TwE w;
    w.w128 = Wsh[lane];
    #pragma unroll
    for (int i = 0; i < 5; i++) {
        int h = 32 >> i;
        float2 t = Wsh[(lane & (h - 1)) << (i + 1)];
        w.we[i] = (lane & h) ? t : make_float2(1.0f, 0.0f);
    }
    return w;
}

__device__ __forceinline__ void bstage(float2& v, float2 o, float s, float2 we) {
    float tx = fmaf(s, v.x, o.x);
    float ty = fmaf(s, v.y, o.y);
    v = make_float2(tx * we.x - ty * we.y, tx * we.y + ty * we.x);
}
// variant for permlane stages where we hold (lo, hi) explicitly:
// low lanes (s=+1): lo+hi ; high lanes (s=-1): lo-hi ; then * we
__device__ __forceinline__ void bstage_lh(float2& v, float2 lo, float2 hi, float s, float2 we) {
    float tx = fmaf(s, hi.x, lo.x);
    float ty = fmaf(s, hi.y, lo.y);
    v = make_float2(tx * we.x - ty * we.y, tx * we.y + ty * we.x);
}

// Two independent 128-pt DIF FFTs, interleaved stage-by-stage. 5 of 6
// cross-lane stages run on the VALU pipe (permlane_swap / DPP, fp32 exact);
// only xor-4 uses one ds_swizzle per complex (packed bf16).
// Pair A: lane holds a0=x[lane], a1=x[lane+64]; same for pair B.
// Output: a0 = X[2*rev6(lane)], a1 = X[2*rev6(lane)+1].
__device__ __forceinline__ void fft128x2(float2& a0, float2& a1,
                                         float2& b0, float2& b1,
                                         const TwE& w, int lane) {
    float2 d;
    d  = make_float2(a0.x - a1.x, a0.y - a1.y);
    a0 = make_float2(a0.x + a1.x, a0.y + a1.y);
    a1 = cmul(d, w.w128);
    d  = make_float2(b0.x - b1.x, b0.y - b1.y);
    b0 = make_float2(b0.x + b1.x, b0.y + b1.y);
    b1 = cmul(d, w.w128);

    {   // h = 32 : permlane32_swap
        float s = (lane & 32) ? -1.0f : 1.0f;
        float2 l0, h0, l1, h1, l2, h2, l3, h3;
        plswap32(a0, l0, h0); plswap32(a1, l1, h1);
        plswap32(b0, l2, h2); plswap32(b1, l3, h3);
        bstage_lh(a0, l0, h0, s, w.we[0]);
        bstage_lh(a1, l1, h1, s, w.we[0]);
        bstage_lh(b0, l2, h2, s, w.we[0]);
        bstage_lh(b1, l3, h3, s, w.we[0]);
    }
    {   // h = 16 : permlane16_swap
        float s = (lane & 16) ? -1.0f : 1.0f;
        float2 l0, h0, l1, h1, l2, h2, l3, h3;
        plswap16(a0, l0, h0); plswap16(a1, l1, h1);
        plswap16(b0, l2, h2); plswap16(b1, l3, h3);
        bstage_lh(a0, l0, h0, s, w.we[1]);
        bstage_lh(a1, l1, h1, s, w.we[1]);
        bstage_lh(b0, l2, h2, s, w.we[1]);
        bstage_lh(b1, l3, h3, s, w.we[1]);
    }
    {   // h = 8 : DPP row_ror:8
        float s = (lane & 8) ? -1.0f : 1.0f;
        float2 o0 = dpp_xor<0x128>(a0), o1 = dpp_xor<0x128>(a1);
        float2 o2 = dpp_xor<0x128>(b0), o3 = dpp_xor<0x128>(b1);
        bstage(a0, o0, s, w.we[2]); bstage(a1, o1, s, w.we[2]);
        bstage(b0, o2, s, w.we[2]); bstage(b1, o3, s, w.we[2]);
    }
    {   // h = 4 : single LDS swizzle stage (packed bf16)
        float s = (lane & 4) ? -1.0f : 1.0f;
        float2 o0 = swz4(a0), o1 = swz4(a1), o2 = swz4(b0), o3 = swz4(b1);
        bstage(a0, o0, s, w.we[3]); bstage(a1, o1, s, w.we[3]);
        bstage(b0, o2, s, w.we[3]); bstage(b1, o3, s, w.we[3]);
    }
    {   // h = 2 : DPP quad_perm [2,3,0,1]
        float s = (lane & 2) ? -1.0f : 1.0f;
        float2 o0 = dpp_xor<0x4E>(a0), o1 = dpp_xor<0x4E>(a1);
        float2 o2 = dpp_xor<0x4E>(b0), o3 = dpp_xor<0x4E>(b1);
        bstage(a0, o0, s, w.we[4]); bstage(a1, o1, s, w.we[4]);
        bstage(b0, o2, s, w.we[4]); bstage(b1, o3, s, w.we[4]);
    }
    {   // h = 1 : DPP quad_perm [1,0,3,2], final butterfly (no twiddle)
        float s = (lane & 1) ? -1.0f : 1.0f;
        float2 o0 = dpp_xor<0xB1>(a0), o1 = dpp_xor<0xB1>(a1);
        float2 o2 = dpp_xor<0xB1>(b0), o3 = dpp_xor<0xB1>(b1);
        a0 = make_float2(fmaf(s, a0.x, o0.x), fmaf(s, a0.y, o0.y));
        a1 = make_float2(fmaf(s, a1.x, o1.x), fmaf(s, a1.y, o1.y));
        b0 = make_float2(fmaf(s, b0.x, o2.x), fmaf(s, b0.y, o2.y));
        b1 = make_float2(fmaf(s, b1.x, o3.x), fmaf(s, b1.y, o3.y));
    }
}

// slot index holding frequency k after fft128
__device__ __forceinline__ int slot_of(int k) {
    return (k & 1) ? 64 + rev6(k >> 1) : rev6(k >> 1);
}

// ---- Pass 1: packed x-FFT (L = mo + i*tg), Hermitian unpack, keep kx=0..64 ----
// grid: nb*128(z)*8(ytile) blocks of 256. Output (bf16x2): [vol][b][kx][z][y].
__global__ __launch_bounds__(256, 8)
void fft_x_pack_kernel(const float* __restrict__ in0, const float* __restrict__ in1,
                       unsigned int* __restrict__ wso, unsigned int* __restrict__ wst,
                       int b0, float scale)
{
    __shared__ float2 tile[16][129];
    __shared__ float2 Wsh[64];
    int tid = threadIdx.x, lane = tid & 63, wave = tid >> 6;
    int bi = blockIdx.x;
    int yt = bi & 7, z = (bi >> 3) & 127, b = bi >> 10;
    build_W(Wsh, tid);
    __syncthreads();
    TwE w = make_twe(Wsh, lane);

    // prefetch all 4 lines (8 float2) before any FFT so the global-load
    // latency overlaps across both fft128x2 calls
    size_t src_base = (size_t)(b0 + b) * VOL + (size_t)z * PLANE;
    float2 r0a, r0b, r1a, r1b, r2a, r2b, r3a, r3b;
    {
        const float* p00 = in0 + src_base + (size_t)(yt * 16 + wave * 4) * N;
        const float* p10 = in1 + src_base + (size_t)(yt * 16 + wave * 4) * N;
        r0a = make_float2(p00[lane]          * scale, p10[lane]          * scale);
        r0b = make_float2(p00[lane + 64]     * scale, p10[lane + 64]     * scale);
        r1a = make_float2(p00[N + lane]      * scale, p10[N + lane]      * scale);
        r1b = make_float2(p00[N + lane + 64] * scale, p10[N + lane + 64] * scale);
        r2a = make_float2(p00[2*N + lane]      * scale, p10[2*N + lane]      * scale);
        r2b = make_float2(p00[2*N + lane + 64] * scale, p10[2*N + lane + 64] * scale);
        r3a = make_float2(p00[3*N + lane]      * scale, p10[3*N + lane]      * scale);
        r3b = make_float2(p00[3*N + lane + 64] * scale, p10[3*N + lane + 64] * scale);
    }
    fft128x2(r0a, r0b, r1a, r1b, w, lane);
    fft128x2(r2a, r2b, r3a, r3b, w, lane);
    int j0 = wave * 4;
    tile[j0    ][lane]      = r0a;  tile[j0    ][lane + 64] = r0b;
    tile[j0 + 1][lane]      = r1a;  tile[j0 + 1][lane + 64] = r1b;
    tile[j0 + 2][lane]      = r2a;  tile[j0 + 2][lane + 64] = r2b;
    tile[j0 + 3][lane]      = r3a;  tile[j0 + 3][lane + 64] = r3b;
    __syncthreads();

    // unpack: O = (L(k)+conj(L(-k)))/2 ; T = (L(k)-conj(L(-k)))/(2i)
    size_t dst_off = (size_t)b * NKX * PLANE + (size_t)z * N + yt * 16;
    for (int idx = tid; idx < 2 * NKX * 16; idx += 256) {
        int j   = idx & 15;
        int c   = idx >> 4;              // 0..129
        int vol = (c >= NKX);
        int kx  = c - vol * NKX;
        int mk  = (128 - kx) & 127;
        float2 a  = tile[j][slot_of(kx)];
        float2 bm = tile[j][slot_of(mk)];
        float2 v = vol ? make_float2(0.5f * (a.y + bm.y), 0.5f * (bm.x - a.x))
                       : make_float2(0.5f * (a.x + bm.x), 0.5f * (a.y - bm.y));
        unsigned int* dst = vol ? wst : wso;
        dst[dst_off + (size_t)kx * PLANE + j] = pack_bf2(v);
    }
}

// ---- Fused pass 2: y-FFT + z-FFT + shell accumulation per (b, kx) plane ----
// grid: nb*64 blocks of 1024 (16 waves). Exactly 2 blocks/CU * 256 CUs when
// nb=8 -> no straggler tail (the old nb*65 grid left 8 blocks for a second
// round that cost ~45% of the kernel). Slot 63 handles BOTH kx=63 and kx=64
// (the two cheapest planes: phase-B live fraction ~20%).
// LDS plane as fp8x2 (values x16 from pass1's scale; all three shell sums
// scale by exactly 256, undone at flush). Swizzle col = (z + ky) & 127.
__global__ __launch_bounds__(1024, 8)
void fft_yz_acc_kernel(const unsigned int* __restrict__ wsv, float* __restrict__ gacc,
                       int nb, int b0)
{
    __shared__ unsigned short tile[2][128][128];   // 65536 B
    __shared__ float2 Wsh[64];
    __shared__ float accn[NSHELL], accp[NSHELL], accq[NSHELL];
    int tid = threadIdx.x, lane = tid & 63, wave = tid >> 6;
    int bi = blockIdx.x;
    int kslot = bi / nb;              // 0..63
    int b = bi - kslot * nb;
    int np = (kslot == 63) ? 2 : 1;

    build_W(Wsh, tid);
    __syncthreads();
    TwE w = make_twe(Wsh, lane);
    int nv = nb * NKX;

    int kz0 = 2 * rev6(lane), kz1 = kz0 + 1;
    int cz0 = (kz0 < 64) ? kz0 : kz0 - 128;
    int cz1 = (kz1 < 64) ? kz1 : kz1 - 128;
    int z20 = cz0 * cz0, z21 = cz1 * cz1;

    for (int p = 0; p < np; p++) {
        int kx = (kslot < 63) ? kslot : (63 + p);
        if (tid < NSHELL) { accn[tid] = 0.0f; accp[tid] = 0.0f; accq[tid] = 0.0f; }
        __syncthreads();

        // Phase A: 256 y-FFT lines (vol, z); wave handles 16, processed in
        // pairs (adjacent z, same vol: pair never straddles the vol boundary).
        for (int c = 0; c < 16; c += 2) {
            int idx0 = wave * 16 + c;
            int vol = idx0 >> 7, z0 = idx0 & 127, z1 = z0 + 1;
            const unsigned int* p0 = wsv + ((size_t)vol * nv + (size_t)b * NKX + kx) * PLANE + (size_t)z0 * N;
            const unsigned int* p1 = p0 + N;
            float2 a0 = unpack_bf2(p0[lane]);
            float2 a1 = unpack_bf2(p0[lane + 64]);
            float2 c0 = unpack_bf2(p1[lane]);
            float2 c1 = unpack_bf2(p1[lane + 64]);
            fft128x2(a0, a1, c0, c1, w, lane);
            int ky0 = 2 * rev6(lane);                // a1/c1 hold ky0+1
            tile[vol][ky0][(z0 + ky0) & 127]         = pack_f8(a0);
            tile[vol][ky0 + 1][(z0 + ky0 + 1) & 127] = pack_f8(a1);
            tile[vol][ky0][(z1 + ky0) & 127]         = pack_f8(c0);
            tile[vol][ky0 + 1][(z1 + ky0 + 1) & 127] = pack_f8(c1);
        }
        __syncthreads();

        // Phase B: z-FFT per live ky line (o and t interleaved) + accumulate
        int kx2 = kx * kx;
        for (int c = 0; c < 8; c++) {
            int ky = wave + 16 * c;
            int cy = (ky < 64) ? ky : ky - 128;
            int base2 = kx2 + cy * cy;
            if (base2 > 4224) continue;              // whole z-line outside sphere
            int c0 = (lane + ky) & 127;
            int c1 = (lane + 64 + ky) & 127;
            float2 o0 = unpack_f8(tile[0][ky][c0]);
            float2 o1 = unpack_f8(tile[0][ky][c1]);
            float2 t0 = unpack_f8(tile[1][ky][c0]);
            float2 t1 = unpack_f8(tile[1][ky][c1]);
            fft128x2(o0, o1, t0, t1, w, lane);
            int r20 = base2 + z20;
            if (r20 <= 4224) {
                int sh = (int)sqrtf((float)r20);
                if ((sh + 1) * (sh + 1) <= r20) sh++;
                else if (sh * sh > r20) sh--;
                atomicAdd(&accn[sh], o0.x * t0.x + o0.y * t0.y);
                atomicAdd(&accp[sh], o0.x * o0.x + o0.y * o0.y);
                atomicAdd(&accq[sh], t0.x * t0.x + t0.y * t0.y);
            }
            int r21 = base2 + z21;
            if (r21 <= 4224) {
                int sh = (int)sqrtf((float)r21);
                if ((sh + 1) * (sh + 1) <= r21) sh++;
                else if (sh * sh > r21) sh--;
                atomicAdd(&accn[sh], o1.x * t1.x + o1.y * t1.y);
                atomicAdd(&accp[sh], o1.x * o1.x + o1.y * o1.y);
                atomicAdd(&accq[sh], t1.x * t1.x + t1.y * t1.y);
            }
        }
        __syncthreads();

        if (tid < NSHELL) {
            // Hermitian mirror weight * 1/256 (undo the x16 amplitude pre-scale)
            float wgt = ((kx == 0 || kx == 64) ? 1.0f : 2.0f) * (1.0f / 256.0f);
            float* g = gacc + (size_t)(b0 + b) * ACC_STRIDE;
            atomicAdd(&g[tid],              wgt * accn[tid]);
            atomicAdd(&g[NSHELL + tid],     wgt * accp[tid]);
            atomicAdd(&g[2 * NSHELL + tid], wgt * accq[tid]);
        }
        if (p + 1 < np) __syncthreads();   // protect acc re-zero + tile reuse
    }
}

// ---------------- Finalize: fsc -> loss scalar -----------------------------
__global__ void finalize_kernel(const float* __restrict__ gacc,
                                float* __restrict__ out)
{
    int lane = threadIdx.x;   // 64 threads, shell = lane+1 (1..64)
    int sh = lane + 1;
    float total = 0.0f;
    #pragma unroll
    for (int b = 0; b < 8; b++) {
        const float* g = gacc + b * ACC_STRIDE;
        float num = g[sh];
        float po  = g[NSHELL + sh];
        float pt  = g[2 * NSHELL + sh];
        float fsc = num / sqrtf(po * pt + 1e-6f);
        fsc = fminf(1.0f, fmaxf(-1.0f, fsc));
        total += fsc;
    }
    #pragma unroll
    for (int off = 32; off; off >>= 1) total += __shfl_down(total, off);
    if (lane == 0) out[0] = 1.0f - total / (64.0f * 8.0f);
}

extern "C" void kernel_launch(void* const* d_in, const int* in_sizes, int n_in,
                              void* d_out, int out_size, void* d_ws, size_t ws_size,
                              hipStream_t stream) {
    const float* in0 = (const float*)d_in[0];   // model_output (8,1,128,128,128)
    const float* in1 = (const float*)d_in[1];   // target
    float* gacc = (float*)d_ws;                 // 8*195 floats
    unsigned int* wsA = (unsigned int*)((char*)d_ws + 8192);

    hipMemsetAsync(d_ws, 0, 8 * ACC_STRIDE * sizeof(float), stream);

    size_t avail = (ws_size > 8192) ? ws_size - 8192 : 0;
    size_t per_batch = 2ull * NKX * PLANE * sizeof(unsigned int);   // ~8.5 MB
    int NB = (int)(avail / per_batch);
    if (NB > 8) NB = 8;
    if (NB < 1) NB = 1;

    // 16 / sqrt(128^3): ortho norm plus x16 amplitude pre-scale so the fp8
    // LDS plane sits in e4m3's sweet spot; shell sums are x256, undone at flush.
    const float scale = 1.1048543456039804e-2f;

    for (int b0 = 0; b0 < 8; b0 += NB) {
        int nb = (8 - b0 < NB) ? (8 - b0) : NB;
        size_t plane_cnt = (size_t)nb * NKX * PLANE;
        unsigned int* wso = wsA;                 // [vol][b][kx][z][y] bf16x2
        unsigned int* wst = wsA + plane_cnt;
        fft_x_pack_kernel<<<dim3(nb * 1024), dim3(256), 0, stream>>>(in0, in1, wso, wst, b0, scale);
        fft_yz_acc_kernel<<<dim3(nb * 64), dim3(1024), 0, stream>>>(wsA, gacc, nb, b0);
    }
    finalize_kernel<<<dim3(1), dim3(64), 0, stream>>>(gacc, (float*)d_out);
}

// Round 2
// 279.320 us; speedup vs baseline: 1.0645x; 1.0011x over previous
//
#include <hip/hip_runtime.h>
#include <math.h>

#define N 128
#define VOL (N*N*N)            // 2097152
#define PLANE (N*N)            // 16384
#define NKX 65                 // kept x-frequencies 0..64 (Hermitian half)
#define NSHELL 65              // shells 0..64
#define ACC_STRIDE 195         // 3*65 per batch

// packed complex: .x = re, .y = im. Vector ops lower to v_pk_*_f32 (dual-issue
// fp32 on CDNA), halving VALU instruction count of the butterfly core.
typedef float cplx __attribute__((ext_vector_type(2)));

__device__ __forceinline__ int rev6(int x) { return (int)(__brev((unsigned)x) >> 26); }

// complex multiply by twiddle w=(c,s): r = a*c + swap(a)*(-s, s)
// -> 1 v_pk_mul + 1 v_pk_fma (swap/neg fold into op_sel / neg_lo modifiers)
__device__ __forceinline__ cplx cmulw(cplx a, cplx w) {
    cplx sw = __builtin_shufflevector(a, a, 1, 0);
    return __builtin_elementwise_fma(sw, (cplx){-w.y, w.y}, a * w.x);
}

// ---- cross-lane exchange layer (VALU-pipe, no LDS except xor-4) ----
__device__ __forceinline__ void plswap32(cplx v, cplx& lo, cplx& hi) {
    float ax = v.x, bx = v.x, ay = v.y, by = v.y;
    asm("v_permlane32_swap_b32 %0, %1" : "+v"(ax), "+v"(bx));
    asm("v_permlane32_swap_b32 %0, %1" : "+v"(ay), "+v"(by));
    lo = (cplx){ax, ay}; hi = (cplx){bx, by};
}
__device__ __forceinline__ void plswap16(cplx v, cplx& lo, cplx& hi) {
    float ax = v.x, bx = v.x, ay = v.y, by = v.y;
    asm("v_permlane16_swap_b32 %0, %1" : "+v"(ax), "+v"(bx));
    asm("v_permlane16_swap_b32 %0, %1" : "+v"(ay), "+v"(by));
    lo = (cplx){ax, ay}; hi = (cplx){bx, by};
}
// h=8: DPP row_ror:8 (== xor8 within 16-lane rows); h=2/1: DPP quad_perm.
template<int CTRL>
__device__ __forceinline__ cplx dpp_xor(cplx v) {
    int rx = __builtin_amdgcn_mov_dpp(__float_as_int(v.x), CTRL, 0xF, 0xF, true);
    int ry = __builtin_amdgcn_mov_dpp(__float_as_int(v.y), CTRL, 0xF, 0xF, true);
    return (cplx){__int_as_float(rx), __int_as_float(ry)};
}
// h=4: no DPP/permlane pattern for xor4 -> single ds_swizzle on packed bf16
__device__ __forceinline__ cplx swz4(cplx v) {
    unsigned p = __builtin_amdgcn_perm(__float_as_uint(v.y), __float_as_uint(v.x), 0x07060302u);
    unsigned q = (unsigned)__builtin_amdgcn_ds_swizzle((int)p, 0x101F);  // xor 4
    return (cplx){__uint_as_float(q << 16), __uint_as_float(q & 0xFFFF0000u)};
}

// bf16x2 pack (RNE) / unpack: complex value in one uint (re low, im high)
__device__ __forceinline__ unsigned int pack_bf2(cplx v) {
    unsigned int r = __float_as_uint(v.x);
    unsigned int i = __float_as_uint(v.y);
    r = (r + 0x7FFFu + ((r >> 16) & 1u)) >> 16;
    i = (i + 0x7FFFu + ((i >> 16) & 1u)) & 0xFFFF0000u;
    return i | r;
}
__device__ __forceinline__ cplx unpack_bf2(unsigned int u) {
    return (cplx){__uint_as_float(u << 16), __uint_as_float(u & 0xFFFF0000u)};
}

// fp8 e4m3 packed complex (re byte0, im byte1) for the in-LDS plane
__device__ __forceinline__ unsigned short pack_f8(cplx v) {
    int p = __builtin_amdgcn_cvt_pk_fp8_f32(v.x, v.y, 0, false);
    return (unsigned short)(p & 0xFFFF);
}
__device__ __forceinline__ cplx unpack_f8(unsigned short u) {
    auto r = __builtin_amdgcn_cvt_pk_f32_fp8((int)u, false);
    return (cplx){r[0], r[1]};
}

// 64-entry twiddle table W[m] = e^{-2*pi*i*m/128}, built once per block
__device__ __forceinline__ void build_W(cplx* Wsh, int tid) {
    if (tid < 64) {
        float s, c;
        sincosf(-6.283185307179586f * (float)tid / 128.0f, &s, &c);
        Wsh[tid] = (cplx){c, s};
    }
}

// Per-lane effective twiddles: w128 for the register stage; we[i] is the
// stage twiddle for high lanes and (1,0) for low lanes (branchless butterfly).
struct TwE { cplx w128; cplx we[5]; };

__device__ __forceinline__ TwE make_twe(const cplx* Wsh, int lane) {
    TwE w;
    w.w128 = Wsh[lane];
    #pragma unroll
    for (int i = 0; i < 5; i++) {
        int h = 32 >> i;
        cplx t = Wsh[(lane & (h - 1)) << (i + 1)];
        w.we[i] = (lane & h) ? t : (cplx){1.0f, 0.0f};
    }
    return w;
}

// t = s*v + o (1 pk_fma), then *we (2 pk ops)
__device__ __forceinline__ void bstage(cplx& v, cplx o, float s, cplx we) {
    cplx t = __builtin_elementwise_fma((cplx){s, s}, v, o);
    v = cmulw(t, we);
}
// permlane variant where (lo, hi) are explicit
__device__ __forceinline__ void bstage_lh(cplx& v, cplx lo, cplx hi, float s, cplx we) {
    cplx t = __builtin_elementwise_fma((cplx){s, s}, hi, lo);
    v = cmulw(t, we);
}

// Two independent 128-pt DIF FFTs, interleaved stage-by-stage. 5 of 6
// cross-lane stages run on the VALU pipe (permlane_swap / DPP, fp32 exact);
// only xor-4 uses one ds_swizzle per complex (packed bf16). All butterfly
// arithmetic is packed-fp32 (v_pk_*).
// Pair A: lane holds a0=x[lane], a1=x[lane+64]; same for pair B.
// Output: a0 = X[2*rev6(lane)], a1 = X[2*rev6(lane)+1].
__device__ __forceinline__ void fft128x2(cplx& a0, cplx& a1,
                                         cplx& b0, cplx& b1,
                                         const TwE& w, int lane) {
    cplx d;
    d  = a0 - a1;
    a0 = a0 + a1;
    a1 = cmulw(d, w.w128);
    d  = b0 - b1;
    b0 = b0 + b1;
    b1 = cmulw(d, w.w128);

    {   // h = 32 : permlane32_swap
        float s = (lane & 32) ? -1.0f : 1.0f;
        cplx l0, h0, l1, h1, l2, h2, l3, h3;
        plswap32(a0, l0, h0); plswap32(a1, l1, h1);
        plswap32(b0, l2, h2); plswap32(b1, l3, h3);
        bstage_lh(a0, l0, h0, s, w.we[0]);
        bstage_lh(a1, l1, h1, s, w.we[0]);
        bstage_lh(b0, l2, h2, s, w.we[0]);
        bstage_lh(b1, l3, h3, s, w.we[0]);
    }
    {   // h = 16 : permlane16_swap
        float s = (lane & 16) ? -1.0f : 1.0f;
        cplx l0, h0, l1, h1, l2, h2, l3, h3;
        plswap16(a0, l0, h0); plswap16(a1, l1, h1);
        plswap16(b0, l2, h2); plswap16(b1, l3, h3);
        bstage_lh(a0, l0, h0, s, w.we[1]);
        bstage_lh(a1, l1, h1, s, w.we[1]);
        bstage_lh(b0, l2, h2, s, w.we[1]);
        bstage_lh(b1, l3, h3, s, w.we[1]);
    }
    {   // h = 8 : DPP row_ror:8
        float s = (lane & 8) ? -1.0f : 1.0f;
        cplx o0 = dpp_xor<0x128>(a0), o1 = dpp_xor<0x128>(a1);
        cplx o2 = dpp_xor<0x128>(b0), o3 = dpp_xor<0x128>(b1);
        bstage(a0, o0, s, w.we[2]); bstage(a1, o1, s, w.we[2]);
        bstage(b0, o2, s, w.we[2]); bstage(b1, o3, s, w.we[2]);
    }
    {   // h = 4 : single LDS swizzle stage (packed bf16)
        float s = (lane & 4) ? -1.0f : 1.0f;
        cplx o0 = swz4(a0), o1 = swz4(a1), o2 = swz4(b0), o3 = swz4(b1);
        bstage(a0, o0, s, w.we[3]); bstage(a1, o1, s, w.we[3]);
        bstage(b0, o2, s, w.we[3]); bstage(b1, o3, s, w.we[3]);
    }
    {   // h = 2 : DPP quad_perm [2,3,0,1]
        float s = (lane & 2) ? -1.0f : 1.0f;
        cplx o0 = dpp_xor<0x4E>(a0), o1 = dpp_xor<0x4E>(a1);
        cplx o2 = dpp_xor<0x4E>(b0), o3 = dpp_xor<0x4E>(b1);
        bstage(a0, o0, s, w.we[4]); bstage(a1, o1, s, w.we[4]);
        bstage(b0, o2, s, w.we[4]); bstage(b1, o3, s, w.we[4]);
    }
    {   // h = 1 : DPP quad_perm [1,0,3,2], final butterfly (no twiddle)
        float s = (lane & 1) ? -1.0f : 1.0f;
        cplx o0 = dpp_xor<0xB1>(a0), o1 = dpp_xor<0xB1>(a1);
        cplx o2 = dpp_xor<0xB1>(b0), o3 = dpp_xor<0xB1>(b1);
        cplx sv = (cplx){s, s};
        a0 = __builtin_elementwise_fma(sv, a0, o0);
        a1 = __builtin_elementwise_fma(sv, a1, o1);
        b0 = __builtin_elementwise_fma(sv, b0, o2);
        b1 = __builtin_elementwise_fma(sv, b1, o3);
    }
}

// slot index holding frequency k after fft128
__device__ __forceinline__ int slot_of(int k) {
    return (k & 1) ? 64 + rev6(k >> 1) : rev6(k >> 1);
}

// ---- Pass 1: packed x-FFT (L = mo + i*tg), Hermitian unpack, keep kx=0..64 ----
// grid: nb*128(z)*2(ytile) blocks of 1024 (16 waves, 64 y-lines per block).
// 66KB LDS tile -> 2 blocks/CU = 32 waves (full occupancy). The unpack loop
// computes BOTH O and T from one (a,bm) LDS read pair (LDS reads halved vs
// the 16-line version) and writes 256B-contiguous runs per (kx,z).
// Output (bf16x2): [vol][b][kx][z][y].
__global__ __launch_bounds__(1024, 8)
void fft_x_pack_kernel(const float* __restrict__ in0, const float* __restrict__ in1,
                       unsigned int* __restrict__ wso, unsigned int* __restrict__ wst,
                       int b0, float scale)
{
    __shared__ cplx tile[64][129];
    __shared__ cplx Wsh[64];
    int tid = threadIdx.x, lane = tid & 63, wave = tid >> 6;
    int bi = blockIdx.x;
    int yt = bi & 1, z = (bi >> 1) & 127, b = bi >> 8;
    build_W(Wsh, tid);
    __syncthreads();
    TwE w = make_twe(Wsh, lane);

    size_t src_base = (size_t)(b0 + b) * VOL + (size_t)z * PLANE;
    #pragma unroll
    for (int c = 0; c < 4; c += 2) {
        int j0 = wave * 4 + c, j1 = j0 + 1;
        const float* pa0 = in0 + src_base + (size_t)(yt * 64 + j0) * N;
        const float* pa1 = in1 + src_base + (size_t)(yt * 64 + j0) * N;
        const float* pb0 = in0 + src_base + (size_t)(yt * 64 + j1) * N;
        const float* pb1 = in1 + src_base + (size_t)(yt * 64 + j1) * N;
        cplx a0 = (cplx){pa0[lane]      * scale, pa1[lane]      * scale};
        cplx a1 = (cplx){pa0[lane + 64] * scale, pa1[lane + 64] * scale};
        cplx c0 = (cplx){pb0[lane]      * scale, pb1[lane]      * scale};
        cplx c1 = (cplx){pb0[lane + 64] * scale, pb1[lane + 64] * scale};
        fft128x2(a0, a1, c0, c1, w, lane);
        tile[j0][lane]      = a0;
        tile[j0][lane + 64] = a1;
        tile[j1][lane]      = c0;
        tile[j1][lane + 64] = c1;
    }
    __syncthreads();

    // unpack: O = (L(k)+conj(L(-k)))/2 ; T = (L(k)-conj(L(-k)))/(2i)
    // idx -> (kx, j): j spans 64 consecutive y per wave -> 256B store runs.
    size_t dst_off = (size_t)b * NKX * PLANE + (size_t)z * N + yt * 64;
    for (int idx = tid; idx < NKX * 64; idx += 1024) {
        int j  = idx & 63;
        int kx = idx >> 6;               // wave-uniform (waves are 64-aligned)
        int mk = (128 - kx) & 127;
        cplx a  = tile[j][slot_of(kx)];
        cplx bm = tile[j][slot_of(mk)];
        cplx O = (cplx){0.5f * (a.x + bm.x), 0.5f * (a.y - bm.y)};
        cplx T = (cplx){0.5f * (a.y + bm.y), 0.5f * (bm.x - a.x)};
        size_t d = dst_off + (size_t)kx * PLANE + j;
        wso[d] = pack_bf2(O);
        wst[d] = pack_bf2(T);
    }
}

// ---- Fused pass 2: y-FFT + z-FFT + shell accumulation per (b, kx) plane ----
// grid: nb*64 blocks of 1024 (16 waves). Exactly 2 blocks/CU * 256 CUs when
// nb=8 -> no straggler tail. Slot 63 handles BOTH kx=63 and kx=64 (the two
// cheapest planes: phase-B live fraction ~20%).
// LDS plane as fp8x2 (values x16 from pass1's scale; all three shell sums
// scale by exactly 256, undone at flush). Swizzle col = (z + ky) & 127.
__global__ __launch_bounds__(1024, 8)
void fft_yz_acc_kernel(const unsigned int* __restrict__ wsv, float* __restrict__ gacc,
                       int nb, int b0)
{
    __shared__ unsigned short tile[2][128][128];   // 65536 B
    __shared__ cplx Wsh[64];
    __shared__ float accn[NSHELL], accp[NSHELL], accq[NSHELL];
    int tid = threadIdx.x, lane = tid & 63, wave = tid >> 6;
    int bi = blockIdx.x;
    int kslot = bi / nb;              // 0..63
    int b = bi - kslot * nb;
    int np = (kslot == 63) ? 2 : 1;

    build_W(Wsh, tid);
    __syncthreads();
    TwE w = make_twe(Wsh, lane);
    int nv = nb * NKX;

    int kz0 = 2 * rev6(lane), kz1 = kz0 + 1;
    int cz0 = (kz0 < 64) ? kz0 : kz0 - 128;
    int cz1 = (kz1 < 64) ? kz1 : kz1 - 128;
    int z20 = cz0 * cz0, z21 = cz1 * cz1;

    for (int p = 0; p < np; p++) {
        int kx = (kslot < 63) ? kslot : (63 + p);
        if (tid < NSHELL) { accn[tid] = 0.0f; accp[tid] = 0.0f; accq[tid] = 0.0f; }
        __syncthreads();

        // Phase A: 256 y-FFT lines (vol, z); wave handles 16, processed in
        // pairs (adjacent z, same vol: pair never straddles the vol boundary).
        for (int c = 0; c < 16; c += 2) {
            int idx0 = wave * 16 + c;
            int vol = idx0 >> 7, z0 = idx0 & 127, z1 = z0 + 1;
            const unsigned int* p0 = wsv + ((size_t)vol * nv + (size_t)b * NKX + kx) * PLANE + (size_t)z0 * N;
            const unsigned int* p1 = p0 + N;
            cplx a0 = unpack_bf2(p0[lane]);
            cplx a1 = unpack_bf2(p0[lane + 64]);
            cplx c0 = unpack_bf2(p1[lane]);
            cplx c1 = unpack_bf2(p1[lane + 64]);
            fft128x2(a0, a1, c0, c1, w, lane);
            int ky0 = 2 * rev6(lane);                // a1/c1 hold ky0+1
            tile[vol][ky0][(z0 + ky0) & 127]         = pack_f8(a0);
            tile[vol][ky0 + 1][(z0 + ky0 + 1) & 127] = pack_f8(a1);
            tile[vol][ky0][(z1 + ky0) & 127]         = pack_f8(c0);
            tile[vol][ky0 + 1][(z1 + ky0 + 1) & 127] = pack_f8(c1);
        }
        __syncthreads();

        // Phase B: z-FFT per live ky line (o and t interleaved) + accumulate
        int kx2 = kx * kx;
        for (int c = 0; c < 8; c++) {
            int ky = wave + 16 * c;
            int cy = (ky < 64) ? ky : ky - 128;
            int base2 = kx2 + cy * cy;
            if (base2 > 4224) continue;              // whole z-line outside sphere
            int c0 = (lane + ky) & 127;
            int c1 = (lane + 64 + ky) & 127;
            cplx o0 = unpack_f8(tile[0][ky][c0]);
            cplx o1 = unpack_f8(tile[0][ky][c1]);
            cplx t0 = unpack_f8(tile[1][ky][c0]);
            cplx t1 = unpack_f8(tile[1][ky][c1]);
            fft128x2(o0, o1, t0, t1, w, lane);
            int r20 = base2 + z20;
            if (r20 <= 4224) {
                int sh = (int)sqrtf((float)r20);
                if ((sh + 1) * (sh + 1) <= r20) sh++;
                else if (sh * sh > r20) sh--;
                atomicAdd(&accn[sh], o0.x * t0.x + o0.y * t0.y);
                atomicAdd(&accp[sh], o0.x * o0.x + o0.y * o0.y);
                atomicAdd(&accq[sh], t0.x * t0.x + t0.y * t0.y);
            }
            int r21 = base2 + z21;
            if (r21 <= 4224) {
                int sh = (int)sqrtf((float)r21);
                if ((sh + 1) * (sh + 1) <= r21) sh++;
                else if (sh * sh > r21) sh--;
                atomicAdd(&accn[sh], o1.x * t1.x + o1.y * t1.y);
                atomicAdd(&accp[sh], o1.x * o1.x + o1.y * o1.y);
                atomicAdd(&accq[sh], t1.x * t1.x + t1.y * t1.y);
            }
        }
        __syncthreads();

        if (tid < NSHELL) {
            // Hermitian mirror weight * 1/256 (undo the x16 amplitude pre-scale)
            float wgt = ((kx == 0 || kx == 64) ? 1.0f : 2.0f) * (1.0f / 256.0f);
            float* g = gacc + (size_t)(b0 + b) * ACC_STRIDE;
            atomicAdd(&g[tid],              wgt * accn[tid]);
            atomicAdd(&g[NSHELL + tid],     wgt * accp[tid]);
            atomicAdd(&g[2 * NSHELL + tid], wgt * accq[tid]);
        }
        if (p + 1 < np) __syncthreads();   // protect acc re-zero + tile reuse
    }
}

// ---------------- Finalize: fsc -> loss scalar -----------------------------
__global__ void finalize_kernel(const float* __restrict__ gacc,
                                float* __restrict__ out)
{
    int lane = threadIdx.x;   // 64 threads, shell = lane+1 (1..64)
    int sh = lane + 1;
    float total = 0.0f;
    #pragma unroll
    for (int b = 0; b < 8; b++) {
        const float* g = gacc + b * ACC_STRIDE;
        float num = g[sh];
        float po  = g[NSHELL + sh];
        float pt  = g[2 * NSHELL + sh];
        float fsc = num / sqrtf(po * pt + 1e-6f);
        fsc = fminf(1.0f, fmaxf(-1.0f, fsc));
        total += fsc;
    }
    #pragma unroll
    for (int off = 32; off; off >>= 1) total += __shfl_down(total, off);
    if (lane == 0) out[0] = 1.0f - total / (64.0f * 8.0f);
}

extern "C" void kernel_launch(void* const* d_in, const int* in_sizes, int n_in,
                              void* d_out, int out_size, void* d_ws, size_t ws_size,
                              hipStream_t stream) {
    const float* in0 = (const float*)d_in[0];   // model_output (8,1,128,128,128)
    const float* in1 = (const float*)d_in[1];   // target
    float* gacc = (float*)d_ws;                 // 8*195 floats
    unsigned int* wsA = (unsigned int*)((char*)d_ws + 8192);

    hipMemsetAsync(d_ws, 0, 8 * ACC_STRIDE * sizeof(float), stream);

    size_t avail = (ws_size > 8192) ? ws_size - 8192 : 0;
    size_t per_batch = 2ull * NKX * PLANE * sizeof(unsigned int);   // ~8.5 MB
    int NB = (int)(avail / per_batch);
    if (NB > 8) NB = 8;
    if (NB < 1) NB = 1;

    // 16 / sqrt(128^3): ortho norm plus x16 amplitude pre-scale so the fp8
    // LDS plane sits in e4m3's sweet spot; shell sums are x256, undone at flush.
    const float scale = 1.1048543456039804e-2f;

    for (int b0 = 0; b0 < 8; b0 += NB) {
        int nb = (8 - b0 < NB) ? (8 - b0) : NB;
        size_t plane_cnt = (size_t)nb * NKX * PLANE;
        unsigned int* wso = wsA;                 // [vol][b][kx][z][y] bf16x2
        unsigned int* wst = wsA + plane_cnt;
        fft_x_pack_kernel<<<dim3(nb * 256), dim3(1024), 0, stream>>>(in0, in1, wso, wst, b0, scale);
        fft_yz_acc_kernel<<<dim3(nb * 64), dim3(1024), 0, stream>>>(wsA, gacc, nb, b0);
    }
    finalize_kernel<<<dim3(1), dim3(64), 0, stream>>>(gacc, (float*)d_out);
}